// Round 3
// baseline (394.604 us; speedup 1.0000x reference)
//
#include <hip/hip_runtime.h>
#include <hip/hip_bf16.h>

typedef short short8 __attribute__((ext_vector_type(8)));
typedef float f32x4 __attribute__((ext_vector_type(4)));
typedef unsigned short u16;

#define HD 16
#define DMODEL 1024
#define DKH 64
#define SEQ 2048
#define QSCALE 0.18033688f  // 1/sqrt(64) * log2(e)

typedef const __attribute__((address_space(1))) void gvoid;
typedef __attribute__((address_space(3))) void lvoid;

__device__ inline u16 f2bf(float f) {
  unsigned int x = __builtin_bit_cast(unsigned int, f);
  unsigned int r = (x + 0x7fffu + ((x >> 16) & 1u)) >> 16;
  return (u16)r;
}

__device__ inline float fexp2(float x) {
#if __has_builtin(__builtin_amdgcn_exp2f)
  return __builtin_amdgcn_exp2f(x);
#else
  return __expf(x * 0.69314718f);
#endif
}

// ---------------- weight transpose + fp32->bf16 ----------------
__global__ __launch_bounds__(256) void wt_kernel(const float* __restrict__ W0,
                                                 const float* __restrict__ W1,
                                                 const float* __restrict__ W2,
                                                 const float* __restrict__ W3,
                                                 u16* __restrict__ T) {
  __shared__ float tile[64][65];
  const float* W = blockIdx.z == 0 ? W0 : blockIdx.z == 1 ? W1 : blockIdx.z == 2 ? W2 : W3;
  u16* out = T + (size_t)blockIdx.z * DMODEL * DMODEL;
  int n0 = blockIdx.x * 64, k0 = blockIdx.y * 64;
  int tx = threadIdx.x & 63, ty = threadIdx.x >> 6;
  for (int i = 0; i < 16; i++) {
    int r = ty + i * 4;
    tile[r][tx] = W[(size_t)(k0 + r) * DMODEL + n0 + tx];
  }
  __syncthreads();
  for (int i = 0; i < 16; i++) {
    int r = ty + i * 4;
    out[(size_t)(n0 + r) * DMODEL + k0 + tx] = f2bf(tile[tx][r]);
  }
}

// ---------------- fused QKV GEMM (z selects q/k/v) ----------------
__global__ __launch_bounds__(256) void gemm_qkv(const float* __restrict__ q,
                                                const float* __restrict__ k,
                                                const float* __restrict__ v,
                                                const u16* __restrict__ WT,
                                                const float* __restrict__ bq,
                                                const float* __restrict__ bk,
                                                const float* __restrict__ bv,
                                                u16* __restrict__ Qb,
                                                u16* __restrict__ Kb,
                                                u16* __restrict__ Vtb) {
  __shared__ u16 As[128 * 32];
  __shared__ u16 Bs[128 * 32];
  const int z = blockIdx.z;
  const float* A = z == 0 ? q : z == 1 ? k : v;
  const u16* Bt = WT + (size_t)z * DMODEL * DMODEL;
  const float* bias = z == 0 ? bq : z == 1 ? bk : bv;
  u16* Cv = z == 0 ? Qb : z == 1 ? Kb : Vtb;
  const float scale = z == 0 ? QSCALE : 1.0f;
  const bool vtrans = (z == 2);

  const int tid = threadIdx.x;
  const int lane = tid & 63, wid = tid >> 6;
  const int g = lane >> 4, c = lane & 15;
  const int m0 = blockIdx.y * 128, n0 = blockIdx.x * 128;
  const int wr = (wid >> 1) * 64, wc = (wid & 1) * 64;
  f32x4 acc[4][4] = {};

  for (int kt = 0; kt < 32; ++kt) {
    const int k0 = kt * 32;
    {  // stage A (fp32 -> bf16)
      int c4 = tid & 7, r = tid >> 3;
      for (int p = 0; p < 4; ++p) {
        int row = r + p * 32;
        const float4 a = *(const float4*)(A + (size_t)(m0 + row) * DMODEL + k0 + c4 * 4);
        ushort4 u;
        u.x = f2bf(a.x); u.y = f2bf(a.y); u.z = f2bf(a.z); u.w = f2bf(a.w);
        *(ushort4*)(&As[row * 32 + c4 * 4]) = u;
      }
    }
    {  // stage B via global_load_lds
      int c8 = tid & 3, r = tid >> 2;
      for (int p = 0; p < 2; ++p) {
        int row = r + p * 64;
        __builtin_amdgcn_global_load_lds(
            (gvoid*)(Bt + (size_t)(n0 + row) * DMODEL + k0 + c8 * 8),
            (lvoid*)(&Bs[row * 32 + c8 * 8]), 16, 0, 0);
      }
    }
    __syncthreads();
    short8 af[4], bfr[4];
    for (int mi = 0; mi < 4; ++mi)
      af[mi] = *(const short8*)(&As[(wr + mi * 16 + c) * 32 + g * 8]);
    for (int ni = 0; ni < 4; ++ni)
      bfr[ni] = *(const short8*)(&Bs[(wc + ni * 16 + c) * 32 + g * 8]);
    for (int mi = 0; mi < 4; ++mi)
      for (int ni = 0; ni < 4; ++ni)
        acc[mi][ni] = __builtin_amdgcn_mfma_f32_16x16x32_bf16(af[mi], bfr[ni], acc[mi][ni], 0, 0, 0);
    __syncthreads();
  }

  for (int ni = 0; ni < 4; ++ni) {
    const int colg = n0 + wc + ni * 16 + c;
    const float bv_ = bias[colg];
    for (int mi = 0; mi < 4; ++mi) {
      const int rowb = m0 + wr + mi * 16 + g * 4;
      const int b = rowb >> 11, s = rowb & 2047;
      const int h = colg >> 6, dk = colg & 63;
      if (!vtrans) {
        const size_t base = ((size_t)(b * HD + h)) * SEQ;
        for (int j = 0; j < 4; ++j)
          Cv[(base + s + j) * DKH + dk] = f2bf((acc[mi][ni][j] + bv_) * scale);
      } else {
        const size_t base = ((size_t)(b * HD + h) * DKH + dk) * SEQ + s;
        ushort4 u;
        u.x = f2bf(acc[mi][ni][0] + bv_);
        u.y = f2bf(acc[mi][ni][1] + bv_);
        u.z = f2bf(acc[mi][ni][2] + bv_);
        u.w = f2bf(acc[mi][ni][3] + bv_);
        *(ushort4*)(&Cv[base]) = u;
      }
    }
  }
}

// ---------------- output GEMM: out = Xb(bf16) * WoT^T + bo (fp32) ----------------
__global__ __launch_bounds__(256) void gemm_out(const u16* __restrict__ A,
                                                const u16* __restrict__ Bt,
                                                const float* __restrict__ bias,
                                                float* __restrict__ C) {
  __shared__ u16 As[128 * 32];
  __shared__ u16 Bs[128 * 32];
  const int tid = threadIdx.x;
  const int lane = tid & 63, wid = tid >> 6;
  const int g = lane >> 4, c = lane & 15;
  const int m0 = blockIdx.y * 128, n0 = blockIdx.x * 128;
  const int wr = (wid >> 1) * 64, wc = (wid & 1) * 64;
  f32x4 acc[4][4] = {};

  for (int kt = 0; kt < 32; ++kt) {
    const int k0 = kt * 32;
    int c8 = tid & 3, r = tid >> 2;
    for (int p = 0; p < 2; ++p) {
      int row = r + p * 64;
      __builtin_amdgcn_global_load_lds(
          (gvoid*)(A + (size_t)(m0 + row) * DMODEL + k0 + c8 * 8),
          (lvoid*)(&As[row * 32 + c8 * 8]), 16, 0, 0);
      __builtin_amdgcn_global_load_lds(
          (gvoid*)(Bt + (size_t)(n0 + row) * DMODEL + k0 + c8 * 8),
          (lvoid*)(&Bs[row * 32 + c8 * 8]), 16, 0, 0);
    }
    __syncthreads();
    short8 af[4], bfr[4];
    for (int mi = 0; mi < 4; ++mi)
      af[mi] = *(const short8*)(&As[(wr + mi * 16 + c) * 32 + g * 8]);
    for (int ni = 0; ni < 4; ++ni)
      bfr[ni] = *(const short8*)(&Bs[(wc + ni * 16 + c) * 32 + g * 8]);
    for (int mi = 0; mi < 4; ++mi)
      for (int ni = 0; ni < 4; ++ni)
        acc[mi][ni] = __builtin_amdgcn_mfma_f32_16x16x32_bf16(af[mi], bfr[ni], acc[mi][ni], 0, 0, 0);
    __syncthreads();
  }

  for (int ni = 0; ni < 4; ++ni) {
    const int colg = n0 + wc + ni * 16 + c;
    const float bv = bias[colg];
    for (int mi = 0; mi < 4; ++mi) {
      const int rowb = m0 + wr + mi * 16 + g * 4;
      for (int j = 0; j < 4; ++j)
        C[(size_t)(rowb + j) * DMODEL + colg] = acc[mi][ni][j] + bv;
    }
  }
}

// ---------------- flash attention (pipelined, swizzled P, exp2 softmax) ----------------
// Q (pre-scaled by QSCALE), K: [B*H][S][DK] bf16 ; Vt: [B*H][DK][S] bf16 ; X: [8192][1024] bf16
__global__ __launch_bounds__(256, 3) void attn_kernel(const u16* __restrict__ Q,
                                                      const u16* __restrict__ K,
                                                      const u16* __restrict__ Vt,
                                                      u16* __restrict__ X) {
  __shared__ u16 sP[4][32 * 64];  // wave-private, XOR-swizzled 128B rows
  const int tid = threadIdx.x;
  const int lane = tid & 63, wid = tid >> 6;
  const int g = lane >> 4, c = lane & 15;

  // bijective XCD swizzle: all 16 q-tiles of a head land on one XCD
  const int w = blockIdx.x;
  const int work = (w & 7) * 128 + (w >> 3);
  const int qt = work & 15, bh = work >> 4;

  const int q0 = qt * 128 + wid * 32;
  const u16* qb = Q + (size_t)bh * SEQ * DKH;
  const u16* kb = K + (size_t)bh * SEQ * DKH;
  const u16* vb = Vt + (size_t)bh * DKH * SEQ;

  short8 qf[2][2];
  for (int mi = 0; mi < 2; ++mi)
    for (int kk = 0; kk < 2; ++kk)
      qf[mi][kk] = *(const short8*)(qb + (size_t)(q0 + mi * 16 + c) * DKH + kk * 32 + g * 8);

  // K fragments for tile 0 (persistent registers, refilled each iteration)
  short8 kf[4][2];
#pragma unroll
  for (int ni = 0; ni < 4; ++ni)
#pragma unroll
    for (int kk = 0; kk < 2; ++kk)
      kf[ni][kk] = *(const short8*)(kb + (size_t)(ni * 16 + c) * DKH + kk * 32 + g * 8);

  f32x4 oacc[2][4] = {};
  float mrun[2] = {-1e30f, -1e30f};
  float lrun[2] = {0.f, 0.f};
  char* myP = (char*)&sP[wid][0];
  const int swz = (c & 7) << 4;

  for (int t = 0; t < 32; ++t) {
    const int kv0 = t * 64;
    // V(t) loads issued first — land during QK^T + softmax
    short8 vf[4][2];
#pragma unroll
    for (int ni = 0; ni < 4; ++ni)
#pragma unroll
      for (int kk = 0; kk < 2; ++kk)
        vf[ni][kk] = *(const short8*)(vb + (size_t)(ni * 16 + c) * SEQ + kv0 + kk * 32 + g * 8);

    // S^T = K Q^T : lane owns q = mi*16+c, kv = ni*16 + g*4 + j
    f32x4 sacc[2][4] = {};
    __builtin_amdgcn_s_setprio(1);
#pragma unroll
    for (int kk = 0; kk < 2; ++kk)
#pragma unroll
      for (int mi = 0; mi < 2; ++mi)
#pragma unroll
        for (int ni = 0; ni < 4; ++ni)
          sacc[mi][ni] = __builtin_amdgcn_mfma_f32_16x16x32_bf16(kf[ni][kk], qf[mi][kk], sacc[mi][ni], 0, 0, 0);
    __builtin_amdgcn_s_setprio(0);

    // online softmax (exp2 domain; scale folded into Q)
#pragma unroll
    for (int mi = 0; mi < 2; ++mi) {
      float pm = sacc[mi][0][0];
#pragma unroll
      for (int ni = 0; ni < 4; ++ni)
#pragma unroll
        for (int j = 0; j < 4; ++j) pm = fmaxf(pm, sacc[mi][ni][j]);
      pm = fmaxf(pm, __shfl_xor(pm, 16, 64));
      pm = fmaxf(pm, __shfl_xor(pm, 32, 64));

      const bool skip = __all(pm <= mrun[mi] + 11.5f);
      float a = 1.0f;
      if (!skip) {
        float mnew = fmaxf(mrun[mi], pm);
        a = fexp2(mrun[mi] - mnew);
        mrun[mi] = mnew;
      }
      const float mcur = mrun[mi];
      float rs = 0.f;
#pragma unroll
      for (int ni = 0; ni < 4; ++ni)
#pragma unroll
        for (int j = 0; j < 4; ++j) {
          float p = fexp2(sacc[mi][ni][j] - mcur);
          sacc[mi][ni][j] = p;
          rs += p;
        }
      rs += __shfl_xor(rs, 16, 64);
      rs += __shfl_xor(rs, 32, 64);
      lrun[mi] = lrun[mi] * a + rs;

      // P -> LDS, XOR-swizzled (write: exact 4-phase; read: exact 8-phase)
#pragma unroll
      for (int ni = 0; ni < 4; ++ni) {
        ushort4 u;
        u.x = f2bf(sacc[mi][ni][0]);
        u.y = f2bf(sacc[mi][ni][1]);
        u.z = f2bf(sacc[mi][ni][2]);
        u.w = f2bf(sacc[mi][ni][3]);
        *(ushort4*)(myP + (mi * 16 + c) * 128 + ((ni * 32 + g * 8) ^ swz)) = u;
      }

      if (!skip) {
        float a0 = __shfl(a, 20 * g + 0, 64);
        float a1 = __shfl(a, 20 * g + 1, 64);
        float a2 = __shfl(a, 20 * g + 2, 64);
        float a3 = __shfl(a, 20 * g + 3, 64);
#pragma unroll
        for (int ni = 0; ni < 4; ++ni) {
          oacc[mi][ni][0] *= a0;
          oacc[mi][ni][1] *= a1;
          oacc[mi][ni][2] *= a2;
          oacc[mi][ni][3] *= a3;
        }
      }
    }

    // prefetch K(t+1) into the now-dead kf registers (covered by PV + next QK wait)
    const int kn = kv0 + 64;
#pragma unroll
    for (int ni = 0; ni < 4; ++ni)
#pragma unroll
      for (int kk = 0; kk < 2; ++kk)
        kf[ni][kk] = *(const short8*)(kb + (size_t)(kn + ni * 16 + c) * DKH + kk * 32 + g * 8);

    // P back as A-fragments
    short8 pa[2][2];
#pragma unroll
    for (int mi = 0; mi < 2; ++mi)
#pragma unroll
      for (int kk = 0; kk < 2; ++kk)
        pa[mi][kk] = *(const short8*)(myP + (mi * 16 + c) * 128 + ((kk * 64 + g * 16) ^ swz));

    __builtin_amdgcn_s_setprio(1);
#pragma unroll
    for (int kk = 0; kk < 2; ++kk)
#pragma unroll
      for (int mi = 0; mi < 2; ++mi)
#pragma unroll
        for (int ni = 0; ni < 4; ++ni)
          oacc[mi][ni] = __builtin_amdgcn_mfma_f32_16x16x32_bf16(pa[mi][kk], vf[ni][kk], oacc[mi][ni], 0, 0, 0);
    __builtin_amdgcn_s_setprio(0);
  }

  // epilogue
  const int b = bh >> 4, h = bh & 15;
#pragma unroll
  for (int mi = 0; mi < 2; ++mi) {
    float l0 = __shfl(lrun[mi], 20 * g + 0, 64);
    float l1 = __shfl(lrun[mi], 20 * g + 1, 64);
    float l2 = __shfl(lrun[mi], 20 * g + 2, 64);
    float l3 = __shfl(lrun[mi], 20 * g + 3, 64);
    float inv[4] = {1.f / l0, 1.f / l1, 1.f / l2, 1.f / l3};
#pragma unroll
    for (int ni = 0; ni < 4; ++ni)
#pragma unroll
      for (int j = 0; j < 4; ++j) {
        int s = q0 + mi * 16 + g * 4 + j;
        X[((size_t)(b * SEQ) + s) * DMODEL + h * DKH + ni * 16 + c] =
            f2bf(oacc[mi][ni][j] * inv[j]);
      }
  }
}

extern "C" void kernel_launch(void* const* d_in, const int* in_sizes, int n_in,
                              void* d_out, int out_size, void* d_ws, size_t ws_size,
                              hipStream_t stream) {
  (void)in_sizes; (void)n_in; (void)out_size; (void)ws_size;
  const float* query = (const float*)d_in[0];
  const float* key   = (const float*)d_in[1];
  const float* value = (const float*)d_in[2];
  const float* Wq = (const float*)d_in[3];
  const float* bq = (const float*)d_in[4];
  const float* Wk = (const float*)d_in[5];
  const float* bk = (const float*)d_in[6];
  const float* Wv = (const float*)d_in[7];
  const float* bv = (const float*)d_in[8];
  const float* Wo = (const float*)d_in[9];
  const float* bo = (const float*)d_in[10];
  float* out = (float*)d_out;

  char* ws = (char*)d_ws;
  const size_t MB = 1024 * 1024;
  u16* WT  = (u16*)ws;                 // 4 x 2MB: WqT, WkT, WvT, WoT
  u16* Qb  = (u16*)(ws + 8 * MB);      // 16 MB  [B*H][S][DK]
  u16* Kb  = (u16*)(ws + 24 * MB);     // 16 MB  [B*H][S][DK]
  u16* Vtb = (u16*)(ws + 40 * MB);     // 16 MB  [B*H][DK][S]
  u16* Xb  = (u16*)(ws + 56 * MB);     // 16 MB  [8192][1024]

  wt_kernel<<<dim3(16, 16, 4), 256, 0, stream>>>(Wq, Wk, Wv, Wo, WT);
  gemm_qkv<<<dim3(8, 64, 3), 256, 0, stream>>>(query, key, value, WT, bq, bk, bv, Qb, Kb, Vtb);
  attn_kernel<<<dim3(1024), 256, 0, stream>>>(Qb, Kb, Vtb, Xb);
  gemm_out<<<dim3(8, 64), 256, 0, stream>>>(Xb, WT + 3 * 1048576, bo, out);
}

// Round 4
// 260.830 us; speedup vs baseline: 1.5129x; 1.5129x over previous
//
#include <hip/hip_runtime.h>
#include <hip/hip_bf16.h>

typedef short short8 __attribute__((ext_vector_type(8)));
typedef float f32x4 __attribute__((ext_vector_type(4)));
typedef float f32x16 __attribute__((ext_vector_type(16)));
typedef unsigned short u16;
typedef unsigned int u32;

#define HD 16
#define DMODEL 1024
#define DKH 64
#define SEQ 2048
#define QSCALE 0.18033688f  // 1/sqrt(64) * log2(e)

typedef const __attribute__((address_space(1))) void gvoid;
typedef __attribute__((address_space(3))) void lvoid;

__device__ inline u16 f2bf(float f) {
  unsigned int x = __builtin_bit_cast(unsigned int, f);
  unsigned int r = (x + 0x7fffu + ((x >> 16) & 1u)) >> 16;
  return (u16)r;
}

__device__ inline float fexp2(float x) {
#if __has_builtin(__builtin_amdgcn_exp2f)
  return __builtin_amdgcn_exp2f(x);
#else
  return __expf(x * 0.69314718f);
#endif
}

__device__ inline u32 cvtpk(float lo, float hi_) {
  u32 r;
  asm("v_cvt_pk_bf16_f32 %0, %1, %2" : "=v"(r) : "v"(lo), "v"(hi_));
  return r;
}

__device__ inline f32x16 mfma32(short8 a, short8 b, f32x16 c) {
  return __builtin_amdgcn_mfma_f32_32x32x16_bf16(a, b, c, 0, 0, 0);
}

// ---------------- weight transpose + fp32->bf16 ----------------
__global__ __launch_bounds__(256) void wt_kernel(const float* __restrict__ W0,
                                                 const float* __restrict__ W1,
                                                 const float* __restrict__ W2,
                                                 const float* __restrict__ W3,
                                                 u16* __restrict__ T) {
  __shared__ float tile[64][65];
  const float* W = blockIdx.z == 0 ? W0 : blockIdx.z == 1 ? W1 : blockIdx.z == 2 ? W2 : W3;
  u16* out = T + (size_t)blockIdx.z * DMODEL * DMODEL;
  int n0 = blockIdx.x * 64, k0 = blockIdx.y * 64;
  int tx = threadIdx.x & 63, ty = threadIdx.x >> 6;
  for (int i = 0; i < 16; i++) {
    int r = ty + i * 4;
    tile[r][tx] = W[(size_t)(k0 + r) * DMODEL + n0 + tx];
  }
  __syncthreads();
  for (int i = 0; i < 16; i++) {
    int r = ty + i * 4;
    out[(size_t)(n0 + r) * DMODEL + k0 + tx] = f2bf(tile[tx][r]);
  }
}

// ---------------- fused QKV GEMM (z selects q/k/v) ----------------
__global__ __launch_bounds__(256) void gemm_qkv(const float* __restrict__ q,
                                                const float* __restrict__ k,
                                                const float* __restrict__ v,
                                                const u16* __restrict__ WT,
                                                const float* __restrict__ bq,
                                                const float* __restrict__ bk,
                                                const float* __restrict__ bv,
                                                u16* __restrict__ Qb,
                                                u16* __restrict__ Kb,
                                                u16* __restrict__ Vtb) {
  __shared__ u16 As[128 * 32];
  __shared__ u16 Bs[128 * 32];
  const int z = blockIdx.z;
  const float* A = z == 0 ? q : z == 1 ? k : v;
  const u16* Bt = WT + (size_t)z * DMODEL * DMODEL;
  const float* bias = z == 0 ? bq : z == 1 ? bk : bv;
  u16* Cv = z == 0 ? Qb : z == 1 ? Kb : Vtb;
  const float scale = z == 0 ? QSCALE : 1.0f;
  const bool vtrans = (z == 2);

  const int tid = threadIdx.x;
  const int lane = tid & 63, wid = tid >> 6;
  const int g = lane >> 4, c = lane & 15;
  const int m0 = blockIdx.y * 128, n0 = blockIdx.x * 128;
  const int wr = (wid >> 1) * 64, wc = (wid & 1) * 64;
  f32x4 acc[4][4] = {};

  for (int kt = 0; kt < 32; ++kt) {
    const int k0 = kt * 32;
    {  // stage A (fp32 -> bf16)
      int c4 = tid & 7, r = tid >> 3;
      for (int p = 0; p < 4; ++p) {
        int row = r + p * 32;
        const float4 a = *(const float4*)(A + (size_t)(m0 + row) * DMODEL + k0 + c4 * 4);
        ushort4 u;
        u.x = f2bf(a.x); u.y = f2bf(a.y); u.z = f2bf(a.z); u.w = f2bf(a.w);
        *(ushort4*)(&As[row * 32 + c4 * 4]) = u;
      }
    }
    {  // stage B via global_load_lds
      int c8 = tid & 3, r = tid >> 2;
      for (int p = 0; p < 2; ++p) {
        int row = r + p * 64;
        __builtin_amdgcn_global_load_lds(
            (gvoid*)(Bt + (size_t)(n0 + row) * DMODEL + k0 + c8 * 8),
            (lvoid*)(&Bs[row * 32 + c8 * 8]), 16, 0, 0);
      }
    }
    __syncthreads();
    short8 af[4], bfr[4];
    for (int mi = 0; mi < 4; ++mi)
      af[mi] = *(const short8*)(&As[(wr + mi * 16 + c) * 32 + g * 8]);
    for (int ni = 0; ni < 4; ++ni)
      bfr[ni] = *(const short8*)(&Bs[(wc + ni * 16 + c) * 32 + g * 8]);
    for (int mi = 0; mi < 4; ++mi)
      for (int ni = 0; ni < 4; ++ni)
        acc[mi][ni] = __builtin_amdgcn_mfma_f32_16x16x32_bf16(af[mi], bfr[ni], acc[mi][ni], 0, 0, 0);
    __syncthreads();
  }

  for (int ni = 0; ni < 4; ++ni) {
    const int colg = n0 + wc + ni * 16 + c;
    const float bv_ = bias[colg];
    for (int mi = 0; mi < 4; ++mi) {
      const int rowb = m0 + wr + mi * 16 + g * 4;
      const int b = rowb >> 11, s = rowb & 2047;
      const int h = colg >> 6, dk = colg & 63;
      if (!vtrans) {
        const size_t base = ((size_t)(b * HD + h)) * SEQ;
        for (int j = 0; j < 4; ++j)
          Cv[(base + s + j) * DKH + dk] = f2bf((acc[mi][ni][j] + bv_) * scale);
      } else {
        const size_t base = ((size_t)(b * HD + h) * DKH + dk) * SEQ + s;
        ushort4 u;
        u.x = f2bf(acc[mi][ni][0] + bv_);
        u.y = f2bf(acc[mi][ni][1] + bv_);
        u.z = f2bf(acc[mi][ni][2] + bv_);
        u.w = f2bf(acc[mi][ni][3] + bv_);
        *(ushort4*)(&Cv[base]) = u;
      }
    }
  }
}

// ---------------- output GEMM: out = Xb(bf16) * WoT^T + bo (fp32) ----------------
__global__ __launch_bounds__(256) void gemm_out(const u16* __restrict__ A,
                                                const u16* __restrict__ Bt,
                                                const float* __restrict__ bias,
                                                float* __restrict__ C) {
  __shared__ u16 As[128 * 32];
  __shared__ u16 Bs[128 * 32];
  const int tid = threadIdx.x;
  const int lane = tid & 63, wid = tid >> 6;
  const int g = lane >> 4, c = lane & 15;
  const int m0 = blockIdx.y * 128, n0 = blockIdx.x * 128;
  const int wr = (wid >> 1) * 64, wc = (wid & 1) * 64;
  f32x4 acc[4][4] = {};

  for (int kt = 0; kt < 32; ++kt) {
    const int k0 = kt * 32;
    int c8 = tid & 3, r = tid >> 2;
    for (int p = 0; p < 2; ++p) {
      int row = r + p * 64;
      __builtin_amdgcn_global_load_lds(
          (gvoid*)(A + (size_t)(m0 + row) * DMODEL + k0 + c8 * 8),
          (lvoid*)(&As[row * 32 + c8 * 8]), 16, 0, 0);
      __builtin_amdgcn_global_load_lds(
          (gvoid*)(Bt + (size_t)(n0 + row) * DMODEL + k0 + c8 * 8),
          (lvoid*)(&Bs[row * 32 + c8 * 8]), 16, 0, 0);
    }
    __syncthreads();
    short8 af[4], bfr[4];
    for (int mi = 0; mi < 4; ++mi)
      af[mi] = *(const short8*)(&As[(wr + mi * 16 + c) * 32 + g * 8]);
    for (int ni = 0; ni < 4; ++ni)
      bfr[ni] = *(const short8*)(&Bs[(wc + ni * 16 + c) * 32 + g * 8]);
    for (int mi = 0; mi < 4; ++mi)
      for (int ni = 0; ni < 4; ++ni)
        acc[mi][ni] = __builtin_amdgcn_mfma_f32_16x16x32_bf16(af[mi], bfr[ni], acc[mi][ni], 0, 0, 0);
    __syncthreads();
  }

  for (int ni = 0; ni < 4; ++ni) {
    const int colg = n0 + wc + ni * 16 + c;
    const float bv = bias[colg];
    for (int mi = 0; mi < 4; ++mi) {
      const int rowb = m0 + wr + mi * 16 + g * 4;
      for (int j = 0; j < 4; ++j)
        C[(size_t)(rowb + j) * DMODEL + colg] = acc[mi][ni][j] + bv;
    }
  }
}

// ---------------- flash attention v3: 32x32 MFMA, LDS K/V staging, reg-only P ----------------
// Q (pre-scaled): [B*H][S][64] bf16 ; K: [B*H][S][64] ; Vt: [B*H][64][S] ; X: [8192][1024] bf16
__global__ __launch_bounds__(256, 4) void attn_kernel(const u16* __restrict__ Q,
                                                      const u16* __restrict__ K,
                                                      const u16* __restrict__ Vt,
                                                      u16* __restrict__ X) {
  __shared__ char ldsmem[2][2][8192];  // [buf][K/V][64 rows x 128B, XOR-swizzled]
  const int tid = threadIdx.x;
  const int lane = tid & 63, wid = tid >> 6;
  const int c5 = lane & 31, hi = lane >> 5;

  // bijective XCD swizzle: the 16 q-blocks of a head stay on one XCD
  const int blk = blockIdx.x;                  // 0..1023
  const int work = (blk & 7) * 128 + (blk >> 3);
  const int qt = work & 15, bh = work >> 4;

  const int q0 = qt * 128 + wid * 32;          // wave's 32 q-rows
  const u16* qb = Q + (size_t)bh * SEQ * DKH;
  const char* kbB = (const char*)(K + (size_t)bh * SEQ * DKH);
  const char* vbB = (const char*)(Vt + (size_t)bh * DKH * SEQ);

  // Q B-fragments: col=q=c5, k = ks*16 + hi*8 + i
  short8 qf[4];
#pragma unroll
  for (int ks = 0; ks < 4; ++ks)
    qf[ks] = *(const short8*)(qb + (size_t)(q0 + c5) * DKH + ks * 16 + hi * 8);

  // staging addresses: thread t covers LDS linear bytes t*16 (rows of 128B)
  const int srow = tid >> 3;                   // 0..31
  const int scolb = (tid & 7) << 4;            // 0..112
  const int scol = scolb ^ ((srow & 7) << 4);  // inverse-swizzled source column

  // fragment read column offsets (swizzled)
  const int fswz = (c5 & 7) << 4;
  int cofs[4];
#pragma unroll
  for (int ks = 0; ks < 4; ++ks) cofs[ks] = ((ks * 32 + hi * 16) ^ fswz);

  f32x16 oacc[2] = {};
  float mrun = -1e30f, lrun = 0.f;

  // prologue: stage tile 0 into buf 0
#pragma unroll
  for (int r32 = 0; r32 < 64; r32 += 32) {
    __builtin_amdgcn_global_load_lds(
        (gvoid*)(kbB + (size_t)(r32 + srow) * 128 + scol),
        (lvoid*)(&ldsmem[0][0][(r32 + srow) * 128 + scolb]), 16, 0, 0);
    __builtin_amdgcn_global_load_lds(
        (gvoid*)(vbB + (size_t)(r32 + srow) * (SEQ * 2) + scol),
        (lvoid*)(&ldsmem[0][1][(r32 + srow) * 128 + scolb]), 16, 0, 0);
  }
  __syncthreads();

#pragma unroll 2
  for (int t = 0; t < 32; ++t) {
    const int buf = t & 1;
    // stage next tile into buf^1 (flies under this tile's compute)
    if (t < 31) {
      const size_t kv1 = (size_t)(t + 1) * 64;
#pragma unroll
      for (int r32 = 0; r32 < 64; r32 += 32) {
        __builtin_amdgcn_global_load_lds(
            (gvoid*)(kbB + (kv1 + r32 + srow) * 128 + scol),
            (lvoid*)(&ldsmem[buf ^ 1][0][(r32 + srow) * 128 + scolb]), 16, 0, 0);
        __builtin_amdgcn_global_load_lds(
            (gvoid*)(vbB + (size_t)(r32 + srow) * (SEQ * 2) + kv1 * 2 + scol),
            (lvoid*)(&ldsmem[buf ^ 1][1][(r32 + srow) * 128 + scolb]), 16, 0, 0);
      }
    }

    const char* bK = &ldsmem[buf][0][0];
    const char* bV = &ldsmem[buf][1][0];

    // S^T = K * Q^T : sacc[kt], lane owns q=c5, kv = kt*32 + (r&3)+8*(r>>2)+4*hi
    f32x16 sacc[2] = {};
#pragma unroll
    for (int kt = 0; kt < 2; ++kt) {
      short8 kf[4];
#pragma unroll
      for (int ks = 0; ks < 4; ++ks)
        kf[ks] = *(const short8*)(bK + (kt * 32 + c5) * 128 + cofs[ks]);
#pragma unroll
      for (int ks = 0; ks < 4; ++ks)
        sacc[kt] = mfma32(kf[ks], qf[ks], sacc[kt]);
    }

    // ---- online softmax: lane owns one q-row ----
    float pm = sacc[0][0];
#pragma unroll
    for (int kt = 0; kt < 2; ++kt)
#pragma unroll
      for (int r = 0; r < 16; ++r) pm = fmaxf(pm, sacc[kt][r]);
    pm = fmaxf(pm, __shfl_xor(pm, 32, 64));

    if (!__all(pm <= mrun + 11.5f)) {  // rescale (rare with defer-max)
      float mnew = fmaxf(mrun, pm);
      float a = fexp2(mrun - mnew);
      mrun = mnew;
      lrun *= a;
#pragma unroll
      for (int r = 0; r < 16; ++r) {
        float ar = __shfl(a, (r & 3) + 8 * (r >> 2) + 4 * hi, 64);
        oacc[0][r] *= ar;
        oacc[1][r] *= ar;
      }
    }
    float rs = 0.f;
#pragma unroll
    for (int kt = 0; kt < 2; ++kt)
#pragma unroll
      for (int r = 0; r < 16; ++r) {
        float p = fexp2(sacc[kt][r] - mrun);
        sacc[kt][r] = p;
        rs += p;
      }
    rs += __shfl_xor(rs, 32, 64);
    lrun += rs;

    // ---- pack P to bf16 pairs and redistribute into PV A-fragments (no LDS) ----
    u32 W[2][8], Xw[2][8];
#pragma unroll
    for (int kt = 0; kt < 2; ++kt)
#pragma unroll
      for (int j = 0; j < 8; ++j) {
        W[kt][j] = cvtpk(sacc[kt][2 * j], sacc[kt][2 * j + 1]);
        Xw[kt][j] = __shfl_xor(W[kt][j], 32, 64);
      }
    short8 pa[4];
#pragma unroll
    for (int ks = 0; ks < 4; ++ks) {
      const int kt = ks >> 1, l4 = (ks & 1) * 4;
      u32 m0 = hi ? Xw[kt][l4 + 2] : W[kt][l4 + 0];
      u32 m1 = hi ? Xw[kt][l4 + 3] : W[kt][l4 + 1];
      u32 m2 = hi ? W[kt][l4 + 2] : Xw[kt][l4 + 0];
      u32 m3 = hi ? W[kt][l4 + 3] : Xw[kt][l4 + 1];
      u32 tmp[4] = {m0, m1, m2, m3};
      pa[ks] = *(const short8*)tmp;
    }

    // ---- V fragments + PV ----
    short8 vf[2][4];
#pragma unroll
    for (int dkt = 0; dkt < 2; ++dkt)
#pragma unroll
      for (int ks = 0; ks < 4; ++ks)
        vf[dkt][ks] = *(const short8*)(bV + (dkt * 32 + c5) * 128 + cofs[ks]);
#pragma unroll
    for (int ks = 0; ks < 4; ++ks)
#pragma unroll
      for (int dkt = 0; dkt < 2; ++dkt)
        oacc[dkt] = mfma32(pa[ks], vf[dkt][ks], oacc[dkt]);

    __syncthreads();  // drains vmcnt (next tile staged) + lgkmcnt; protects buf reuse
  }

  // ---- epilogue: X[b*S + q][h*64 + dk] = O / l ----
  const int b = bh >> 4, h = bh & 15;
  const float inv = 1.0f / lrun;
#pragma unroll
  for (int r = 0; r < 16; ++r) {
    const int qrow = (r & 3) + 8 * (r >> 2) + 4 * hi;
    const float linv = __shfl(inv, qrow, 64);
    const size_t rowbase = ((size_t)(b * SEQ) + q0 + qrow) * DMODEL + h * DKH;
#pragma unroll
    for (int dkt = 0; dkt < 2; ++dkt)
      X[rowbase + dkt * 32 + c5] = f2bf(oacc[dkt][r] * linv);
  }
}

extern "C" void kernel_launch(void* const* d_in, const int* in_sizes, int n_in,
                              void* d_out, int out_size, void* d_ws, size_t ws_size,
                              hipStream_t stream) {
  (void)in_sizes; (void)n_in; (void)out_size; (void)ws_size;
  const float* query = (const float*)d_in[0];
  const float* key   = (const float*)d_in[1];
  const float* value = (const float*)d_in[2];
  const float* Wq = (const float*)d_in[3];
  const float* bq = (const float*)d_in[4];
  const float* Wk = (const float*)d_in[5];
  const float* bk = (const float*)d_in[6];
  const float* Wv = (const float*)d_in[7];
  const float* bv = (const float*)d_in[8];
  const float* Wo = (const float*)d_in[9];
  const float* bo = (const float*)d_in[10];
  float* out = (float*)d_out;

  char* ws = (char*)d_ws;
  const size_t MB = 1024 * 1024;
  u16* WT  = (u16*)ws;                 // 4 x 2MB: WqT, WkT, WvT, WoT
  u16* Qb  = (u16*)(ws + 8 * MB);      // 16 MB  [B*H][S][DK]
  u16* Kb  = (u16*)(ws + 24 * MB);     // 16 MB  [B*H][S][DK]
  u16* Vtb = (u16*)(ws + 40 * MB);     // 16 MB  [B*H][DK][S]
  u16* Xb  = (u16*)(ws + 56 * MB);     // 16 MB  [8192][1024]

  wt_kernel<<<dim3(16, 16, 4), 256, 0, stream>>>(Wq, Wk, Wv, Wo, WT);
  gemm_qkv<<<dim3(8, 64, 3), 256, 0, stream>>>(query, key, value, WT, bq, bk, bv, Qb, Kb, Vtb);
  attn_kernel<<<dim3(1024), 256, 0, stream>>>(Qb, Kb, Vtb, Xb);
  gemm_out<<<dim3(8, 64), 256, 0, stream>>>(Xb, WT + 3 * 1048576, bo, out);
}

// Round 5
// 202.257 us; speedup vs baseline: 1.9510x; 1.2896x over previous
//
#include <hip/hip_runtime.h>
#include <hip/hip_bf16.h>

typedef short short8 __attribute__((ext_vector_type(8)));
typedef float f32x4 __attribute__((ext_vector_type(4)));
typedef float f32x16 __attribute__((ext_vector_type(16)));
typedef unsigned short u16;
typedef unsigned int u32;

#define HD 16
#define DMODEL 1024
#define DKH 64
#define SEQ 2048
#define QSCALE 0.18033688f  // 1/sqrt(64) * log2(e)

typedef const __attribute__((address_space(1))) void gvoid;
typedef __attribute__((address_space(3))) void lvoid;

__device__ inline u16 f2bf(float f) {
  unsigned int x = __builtin_bit_cast(unsigned int, f);
  unsigned int r = (x + 0x7fffu + ((x >> 16) & 1u)) >> 16;
  return (u16)r;
}

__device__ inline float fexp2(float x) {
#if __has_builtin(__builtin_amdgcn_exp2f)
  return __builtin_amdgcn_exp2f(x);
#else
  return __expf(x * 0.69314718f);
#endif
}

__device__ inline u32 cvtpk(float lo, float hi_) {
  u32 r;
  asm("v_cvt_pk_bf16_f32 %0, %1, %2" : "=v"(r) : "v"(lo), "v"(hi_));
  return r;
}

__device__ inline f32x4 mfma16(short8 a, short8 b, f32x4 c) {
  return __builtin_amdgcn_mfma_f32_16x16x32_bf16(a, b, c, 0, 0, 0);
}
__device__ inline f32x16 mfma32(short8 a, short8 b, f32x16 c) {
  return __builtin_amdgcn_mfma_f32_32x32x16_bf16(a, b, c, 0, 0, 0);
}

// ---------------- weight transpose + fp32->bf16 ----------------
__global__ __launch_bounds__(256) void wt_kernel(const float* __restrict__ W0,
                                                 const float* __restrict__ W1,
                                                 const float* __restrict__ W2,
                                                 const float* __restrict__ W3,
                                                 u16* __restrict__ T) {
  __shared__ float tile[64][65];
  const float* W = blockIdx.z == 0 ? W0 : blockIdx.z == 1 ? W1 : blockIdx.z == 2 ? W2 : W3;
  u16* out = T + (size_t)blockIdx.z * DMODEL * DMODEL;
  int n0 = blockIdx.x * 64, k0 = blockIdx.y * 64;
  int tx = threadIdx.x & 63, ty = threadIdx.x >> 6;
  for (int i = 0; i < 16; i++) {
    int r = ty + i * 4;
    tile[r][tx] = W[(size_t)(k0 + r) * DMODEL + n0 + tx];
  }
  __syncthreads();
  for (int i = 0; i < 16; i++) {
    int r = ty + i * 4;
    out[(size_t)(n0 + r) * DMODEL + k0 + tx] = f2bf(tile[tx][r]);
  }
}

// ---------------- fused QKV GEMM v2: BK=64, XOR-swizzled LDS, XCD panel clustering ----
// grid: 1536 linear blocks. b%8 = XCD; 8 n-blocks of one (z,m)-panel are consecutive
// slots on ONE XCD -> A panel fetched from HBM once, served 7x from that XCD's L2.
__global__ __launch_bounds__(256, 3) void gemm_qkv(const float* __restrict__ q,
                                                   const float* __restrict__ k,
                                                   const float* __restrict__ v,
                                                   const u16* __restrict__ WT,
                                                   const float* __restrict__ bq,
                                                   const float* __restrict__ bk,
                                                   const float* __restrict__ bv,
                                                   u16* __restrict__ Qb,
                                                   u16* __restrict__ Kb,
                                                   u16* __restrict__ Vtb) {
  __shared__ u16 As[128 * 64];
  __shared__ u16 Bs[128 * 64];
  const int b = blockIdx.x;
  const int xcd = b & 7, slot = b >> 3;
  const int nidx = slot & 7, pl = slot >> 3;   // pl 0..23
  const int pg = xcd * 24 + pl;                // 0..191 = (z, by)
  const int z = pg >> 6, by = pg & 63;

  const float* A = z == 0 ? q : z == 1 ? k : v;
  const u16* Bt = WT + (size_t)z * DMODEL * DMODEL;
  const float* bias = z == 0 ? bq : z == 1 ? bk : bv;
  u16* Cv = z == 0 ? Qb : z == 1 ? Kb : Vtb;
  const float scale = z == 0 ? QSCALE : 1.0f;
  const bool vtrans = (z == 2);

  const int m0 = by * 128, n0 = nidx * 128;
  const int tid = threadIdx.x;
  const int lane = tid & 63, wid = tid >> 6;
  const int g = lane >> 4, c = lane & 15;
  const int wr = (wid >> 1) * 64, wc = (wid & 1) * 64;

  const int trow = tid >> 3;                   // 0..31
  const int tcolb = (tid & 7) << 4;            // byte col 0..112
  const int swr = (c & 7) << 4;                // read swizzle
  f32x4 acc[4][4] = {};

  for (int kt = 0; kt < 16; ++kt) {
    const int k0 = kt * 64;
    // ---- B tile via global_load_lds (linear dest, inverse-swizzled source) ----
#pragma unroll
    for (int p = 0; p < 4; ++p) {
      const int row = p * 32 + trow;
      const int scol = tcolb ^ ((row & 7) << 4);
      __builtin_amdgcn_global_load_lds(
          (gvoid*)((const char*)Bt + ((size_t)(n0 + row) * DMODEL + k0) * 2 + scol),
          (lvoid*)((char*)Bs + row * 128 + tcolb), 16, 0, 0);
    }
    // ---- A tile: fp32 load -> cvt_pk bf16 -> swizzled ds_write_b128 ----
#pragma unroll
    for (int p = 0; p < 4; ++p) {
      const int row = p * 32 + trow;
      const float* src = A + (size_t)(m0 + row) * DMODEL + k0 + (tid & 7) * 8;
      const float4 a0 = *(const float4*)src;
      const float4 a1 = *(const float4*)(src + 4);
      u32 tmp[4] = {cvtpk(a0.x, a0.y), cvtpk(a0.z, a0.w),
                    cvtpk(a1.x, a1.y), cvtpk(a1.z, a1.w)};
      *(uint4*)((char*)As + row * 128 + (tcolb ^ ((row & 7) << 4))) = *(uint4*)tmp;
    }
    __syncthreads();
#pragma unroll
    for (int kk = 0; kk < 2; ++kk) {
      short8 af[4], bfr[4];
#pragma unroll
      for (int mi = 0; mi < 4; ++mi)
        af[mi] = *(const short8*)((const char*)As + (wr + mi * 16 + c) * 128 + ((kk * 64 + g * 16) ^ swr));
#pragma unroll
      for (int ni = 0; ni < 4; ++ni)
        bfr[ni] = *(const short8*)((const char*)Bs + (wc + ni * 16 + c) * 128 + ((kk * 64 + g * 16) ^ swr));
#pragma unroll
      for (int mi = 0; mi < 4; ++mi)
#pragma unroll
        for (int ni = 0; ni < 4; ++ni)
          acc[mi][ni] = mfma16(af[mi], bfr[ni], acc[mi][ni]);
    }
    __syncthreads();
  }

  // ---- epilogue ----
  for (int ni = 0; ni < 4; ++ni) {
    const int colg = n0 + wc + ni * 16 + c;
    const float bv_ = bias[colg];
    for (int mi = 0; mi < 4; ++mi) {
      const int rowb = m0 + wr + mi * 16 + g * 4;
      const int bb = rowb >> 11, s = rowb & 2047;
      const int h = colg >> 6, dk = colg & 63;
      if (!vtrans) {
        const size_t base = ((size_t)(bb * HD + h)) * SEQ;
        for (int j = 0; j < 4; ++j)
          Cv[(base + s + j) * DKH + dk] = f2bf((acc[mi][ni][j] + bv_) * scale);
      } else {
        const size_t base = ((size_t)(bb * HD + h) * DKH + dk) * SEQ + s;
        ushort4 u;
        u.x = f2bf(acc[mi][ni][0] + bv_);
        u.y = f2bf(acc[mi][ni][1] + bv_);
        u.z = f2bf(acc[mi][ni][2] + bv_);
        u.w = f2bf(acc[mi][ni][3] + bv_);
        *(ushort4*)(&Cv[base]) = u;
      }
    }
  }
}

// ---------------- output GEMM v2: bf16 A, BK=64, swizzled, clustered ----------------
// grid: 512 linear blocks. by = xcd*8 + (slot>>3); nidx = slot&7.
__global__ __launch_bounds__(256, 3) void gemm_out(const u16* __restrict__ A,
                                                   const u16* __restrict__ Bt,
                                                   const float* __restrict__ bias,
                                                   float* __restrict__ C) {
  __shared__ u16 As[128 * 64];
  __shared__ u16 Bs[128 * 64];
  const int b = blockIdx.x;
  const int xcd = b & 7, slot = b >> 3;
  const int nidx = slot & 7, pl = slot >> 3;   // pl 0..7
  const int by = xcd * 8 + pl;

  const int m0 = by * 128, n0 = nidx * 128;
  const int tid = threadIdx.x;
  const int lane = tid & 63, wid = tid >> 6;
  const int g = lane >> 4, c = lane & 15;
  const int wr = (wid >> 1) * 64, wc = (wid & 1) * 64;

  const int trow = tid >> 3;
  const int tcolb = (tid & 7) << 4;
  const int swr = (c & 7) << 4;
  f32x4 acc[4][4] = {};

  for (int kt = 0; kt < 16; ++kt) {
    const int k0 = kt * 64;
#pragma unroll
    for (int p = 0; p < 4; ++p) {
      const int row = p * 32 + trow;
      const int scol = tcolb ^ ((row & 7) << 4);
      __builtin_amdgcn_global_load_lds(
          (gvoid*)((const char*)A + ((size_t)(m0 + row) * DMODEL + k0) * 2 + scol),
          (lvoid*)((char*)As + row * 128 + tcolb), 16, 0, 0);
      __builtin_amdgcn_global_load_lds(
          (gvoid*)((const char*)Bt + ((size_t)(n0 + row) * DMODEL + k0) * 2 + scol),
          (lvoid*)((char*)Bs + row * 128 + tcolb), 16, 0, 0);
    }
    __syncthreads();
#pragma unroll
    for (int kk = 0; kk < 2; ++kk) {
      short8 af[4], bfr[4];
#pragma unroll
      for (int mi = 0; mi < 4; ++mi)
        af[mi] = *(const short8*)((const char*)As + (wr + mi * 16 + c) * 128 + ((kk * 64 + g * 16) ^ swr));
#pragma unroll
      for (int ni = 0; ni < 4; ++ni)
        bfr[ni] = *(const short8*)((const char*)Bs + (wc + ni * 16 + c) * 128 + ((kk * 64 + g * 16) ^ swr));
#pragma unroll
      for (int mi = 0; mi < 4; ++mi)
#pragma unroll
        for (int ni = 0; ni < 4; ++ni)
          acc[mi][ni] = mfma16(af[mi], bfr[ni], acc[mi][ni]);
    }
    __syncthreads();
  }

  for (int ni = 0; ni < 4; ++ni) {
    const int colg = n0 + wc + ni * 16 + c;
    const float bv = bias[colg];
    for (int mi = 0; mi < 4; ++mi) {
      const int rowb = m0 + wr + mi * 16 + g * 4;
      for (int j = 0; j < 4; ++j)
        C[(size_t)(rowb + j) * DMODEL + colg] = acc[mi][ni][j] + bv;
    }
  }
}

// ---------------- flash attention v3: 32x32 MFMA, LDS K/V staging, reg-only P ----------------
__global__ __launch_bounds__(256, 4) void attn_kernel(const u16* __restrict__ Q,
                                                      const u16* __restrict__ K,
                                                      const u16* __restrict__ Vt,
                                                      u16* __restrict__ X) {
  __shared__ char ldsmem[2][2][8192];  // [buf][K/V][64 rows x 128B, XOR-swizzled]
  const int tid = threadIdx.x;
  const int lane = tid & 63, wid = tid >> 6;
  const int c5 = lane & 31, hi = lane >> 5;

  const int blk = blockIdx.x;                  // 0..1023
  const int work = (blk & 7) * 128 + (blk >> 3);
  const int qt = work & 15, bh = work >> 4;

  const int q0 = qt * 128 + wid * 32;
  const u16* qb = Q + (size_t)bh * SEQ * DKH;
  const char* kbB = (const char*)(K + (size_t)bh * SEQ * DKH);
  const char* vbB = (const char*)(Vt + (size_t)bh * DKH * SEQ);

  short8 qf[4];
#pragma unroll
  for (int ks = 0; ks < 4; ++ks)
    qf[ks] = *(const short8*)(qb + (size_t)(q0 + c5) * DKH + ks * 16 + hi * 8);

  const int srow = tid >> 3;
  const int scolb = (tid & 7) << 4;
  const int scol = scolb ^ ((srow & 7) << 4);

  const int fswz = (c5 & 7) << 4;
  int cofs[4];
#pragma unroll
  for (int ks = 0; ks < 4; ++ks) cofs[ks] = ((ks * 32 + hi * 16) ^ fswz);

  f32x16 oacc[2] = {};
  float mrun = -1e30f, lrun = 0.f;

#pragma unroll
  for (int r32 = 0; r32 < 64; r32 += 32) {
    __builtin_amdgcn_global_load_lds(
        (gvoid*)(kbB + (size_t)(r32 + srow) * 128 + scol),
        (lvoid*)(&ldsmem[0][0][(r32 + srow) * 128 + scolb]), 16, 0, 0);
    __builtin_amdgcn_global_load_lds(
        (gvoid*)(vbB + (size_t)(r32 + srow) * (SEQ * 2) + scol),
        (lvoid*)(&ldsmem[0][1][(r32 + srow) * 128 + scolb]), 16, 0, 0);
  }
  __syncthreads();

#pragma unroll 2
  for (int t = 0; t < 32; ++t) {
    const int buf = t & 1;
    if (t < 31) {
      const size_t kv1 = (size_t)(t + 1) * 64;
#pragma unroll
      for (int r32 = 0; r32 < 64; r32 += 32) {
        __builtin_amdgcn_global_load_lds(
            (gvoid*)(kbB + (kv1 + r32 + srow) * 128 + scol),
            (lvoid*)(&ldsmem[buf ^ 1][0][(r32 + srow) * 128 + scolb]), 16, 0, 0);
        __builtin_amdgcn_global_load_lds(
            (gvoid*)(vbB + (size_t)(r32 + srow) * (SEQ * 2) + kv1 * 2 + scol),
            (lvoid*)(&ldsmem[buf ^ 1][1][(r32 + srow) * 128 + scolb]), 16, 0, 0);
      }
    }

    const char* bK = &ldsmem[buf][0][0];
    const char* bV = &ldsmem[buf][1][0];

    f32x16 sacc[2] = {};
#pragma unroll
    for (int kt = 0; kt < 2; ++kt) {
      short8 kf[4];
#pragma unroll
      for (int ks = 0; ks < 4; ++ks)
        kf[ks] = *(const short8*)(bK + (kt * 32 + c5) * 128 + cofs[ks]);
#pragma unroll
      for (int ks = 0; ks < 4; ++ks)
        sacc[kt] = mfma32(kf[ks], qf[ks], sacc[kt]);
    }

    float pm = sacc[0][0];
#pragma unroll
    for (int kt = 0; kt < 2; ++kt)
#pragma unroll
      for (int r = 0; r < 16; ++r) pm = fmaxf(pm, sacc[kt][r]);
    pm = fmaxf(pm, __shfl_xor(pm, 32, 64));

    if (!__all(pm <= mrun + 11.5f)) {
      float mnew = fmaxf(mrun, pm);
      float a = fexp2(mrun - mnew);
      mrun = mnew;
      lrun *= a;
#pragma unroll
      for (int r = 0; r < 16; ++r) {
        float ar = __shfl(a, (r & 3) + 8 * (r >> 2) + 4 * hi, 64);
        oacc[0][r] *= ar;
        oacc[1][r] *= ar;
      }
    }
    float rs = 0.f;
#pragma unroll
    for (int kt = 0; kt < 2; ++kt)
#pragma unroll
      for (int r = 0; r < 16; ++r) {
        float p = fexp2(sacc[kt][r] - mrun);
        sacc[kt][r] = p;
        rs += p;
      }
    rs += __shfl_xor(rs, 32, 64);
    lrun += rs;

    u32 W[2][8], Xw[2][8];
#pragma unroll
    for (int kt = 0; kt < 2; ++kt)
#pragma unroll
      for (int j = 0; j < 8; ++j) {
        W[kt][j] = cvtpk(sacc[kt][2 * j], sacc[kt][2 * j + 1]);
        Xw[kt][j] = __shfl_xor(W[kt][j], 32, 64);
      }
    short8 pa[4];
#pragma unroll
    for (int ks = 0; ks < 4; ++ks) {
      const int kt = ks >> 1, l4 = (ks & 1) * 4;
      u32 m0 = hi ? Xw[kt][l4 + 2] : W[kt][l4 + 0];
      u32 m1 = hi ? Xw[kt][l4 + 3] : W[kt][l4 + 1];
      u32 m2 = hi ? W[kt][l4 + 2] : Xw[kt][l4 + 0];
      u32 m3 = hi ? W[kt][l4 + 3] : Xw[kt][l4 + 1];
      u32 tmp[4] = {m0, m1, m2, m3};
      pa[ks] = *(const short8*)tmp;
    }

    short8 vf[2][4];
#pragma unroll
    for (int dkt = 0; dkt < 2; ++dkt)
#pragma unroll
      for (int ks = 0; ks < 4; ++ks)
        vf[dkt][ks] = *(const short8*)(bV + (dkt * 32 + c5) * 128 + cofs[ks]);
#pragma unroll
    for (int ks = 0; ks < 4; ++ks)
#pragma unroll
      for (int dkt = 0; dkt < 2; ++dkt)
        oacc[dkt] = mfma32(pa[ks], vf[dkt][ks], oacc[dkt]);

    __syncthreads();
  }

  const int b = bh >> 4, h = bh & 15;
  const float inv = 1.0f / lrun;
#pragma unroll
  for (int r = 0; r < 16; ++r) {
    const int qrow = (r & 3) + 8 * (r >> 2) + 4 * hi;
    const float linv = __shfl(inv, qrow, 64);
    const size_t rowbase = ((size_t)(b * SEQ) + q0 + qrow) * DMODEL + h * DKH;
#pragma unroll
    for (int dkt = 0; dkt < 2; ++dkt)
      X[rowbase + dkt * 32 + c5] = f2bf(oacc[dkt][r] * linv);
  }
}

extern "C" void kernel_launch(void* const* d_in, const int* in_sizes, int n_in,
                              void* d_out, int out_size, void* d_ws, size_t ws_size,
                              hipStream_t stream) {
  (void)in_sizes; (void)n_in; (void)out_size; (void)ws_size;
  const float* query = (const float*)d_in[0];
  const float* key   = (const float*)d_in[1];
  const float* value = (const float*)d_in[2];
  const float* Wq = (const float*)d_in[3];
  const float* bq = (const float*)d_in[4];
  const float* Wk = (const float*)d_in[5];
  const float* bk = (const float*)d_in[6];
  const float* Wv = (const float*)d_in[7];
  const float* bv = (const float*)d_in[8];
  const float* Wo = (const float*)d_in[9];
  const float* bo = (const float*)d_in[10];
  float* out = (float*)d_out;

  char* ws = (char*)d_ws;
  const size_t MB = 1024 * 1024;
  u16* WT  = (u16*)ws;                 // 4 x 2MB: WqT, WkT, WvT, WoT
  u16* Qb  = (u16*)(ws + 8 * MB);      // 16 MB  [B*H][S][DK]
  u16* Kb  = (u16*)(ws + 24 * MB);     // 16 MB  [B*H][S][DK]
  u16* Vtb = (u16*)(ws + 40 * MB);     // 16 MB  [B*H][DK][S]
  u16* Xb  = (u16*)(ws + 56 * MB);     // 16 MB  [8192][1024]

  wt_kernel<<<dim3(16, 16, 4), 256, 0, stream>>>(Wq, Wk, Wv, Wo, WT);
  gemm_qkv<<<dim3(1536), 256, 0, stream>>>(query, key, value, WT, bq, bk, bv, Qb, Kb, Vtb);
  attn_kernel<<<dim3(1024), 256, 0, stream>>>(Qb, Kb, Vtb, Xb);
  gemm_out<<<dim3(512), 256, 0, stream>>>(Xb, WT + 3 * 1048576, bo, out);
}